// Round 11
// baseline (252.378 us; speedup 1.0000x reference)
//
#include <hip/hip_runtime.h>
#include <stdint.h>

typedef unsigned short u16;
typedef __attribute__((ext_vector_type(8))) __bf16 bf16x8;
typedef __attribute__((ext_vector_type(4))) float f32x4;

__device__ __forceinline__ u16 f2bf(float f) {
  unsigned u = __float_as_uint(f);
  u += 0x7FFF + ((u >> 16) & 1);   // RNE
  return (u16)(u >> 16);
}

__device__ __forceinline__ float bf2f(u16 h) {
  return __uint_as_float(((unsigned)h) << 16);
}

__device__ __forceinline__ void llds16(const u16* g, u16* l) {
  __builtin_amdgcn_global_load_lds(
      (const __attribute__((address_space(1))) void*)g,
      (__attribute__((address_space(3))) void*)l, 16, 0, 0);
}

// ---------------------------------------------------------------------------
// fused cast fp32 -> bf16 for x | wq | wk | wv + zero lsum
// ---------------------------------------------------------------------------
__global__ __launch_bounds__(256) void cast_all(
    const float* __restrict__ x, const float* __restrict__ wq,
    const float* __restrict__ wk, const float* __restrict__ wv,
    u16* __restrict__ xb, u16* __restrict__ wb, float* __restrict__ lsum) {
  int i = blockIdx.x * 256 + threadIdx.x;
  if (i < 8192) lsum[i] = 0.f;        // softmax-denominator accumulator
  const float* src; u16* dst; int off;
  if (i < 2097152)      { src = x;  dst = xb;            off = i; }
  else if (i < 2359296) { src = wq; dst = wb;            off = i - 2097152; }
  else if (i < 2621440) { src = wk; dst = wb + 1048576;  off = i - 2359296; }
  else                  { src = wv; dst = wb + 2097152;  off = i - 2621440; }
  float4 f = ((const float4*)src)[off];
  ushort4 o;
  o.x = f2bf(f.x); o.y = f2bf(f.y); o.z = f2bf(f.z); o.w = f2bf(f.w);
  ((ushort4*)dst)[off] = o;
}

// ---------------------------------------------------------------------------
// QKV GEMM (r0-verbatim gemm_nt, instantiated MODE 0 only).
// 128x128 tile, BK=64, 256 threads = 4 waves (2x2), 64x64 per wave, chunk-XOR
// swizzle (bank-conflict 0), global_load_lds w16.  ISOLATED template (rule
// #19: sharing a core pushed 80->116 VGPR).  Measured 65.6-66.6us / 80 VGPR
// across r8-r10 (control).
// Session ledger: 256^2 8-phase: slower (r1-2).  Decode permutations: null
// (r3-4).  Queues at jobs~blocks: +9us (r8).  64x32 wave tiles: +12us (r9).
// dbuf vs sbuf at >=4 blocks/CU residency: +8us (r10); dbuf only paid at
// 2/CU residency (r7).  This round: single-wave 64x64 blocks for sc/pv.
// ---------------------------------------------------------------------------
template<int MODE>
__global__ __launch_bounds__(256) void gemm_nt(
    const u16* __restrict__ A, long long sA, int lda,
    const u16* __restrict__ B, long long sB, int ldb,
    void* __restrict__ Cp, long long sC, int ldc,
    int K, u16* __restrict__ vt, float scale,
    float* __restrict__ lsum, const int* __restrict__ causalp) {
  const int t = threadIdx.x;
  const int causal = (MODE == 0) ? 1 : causalp[0];

  int rt = blockIdx.x, ct = blockIdx.y;

  const int rowbase = rt * 128;
  const int colbase = ct * 128;
  const u16* Ab = A + (long long)blockIdx.z * sA;
  const u16* Bb = B + (long long)blockIdx.z * sB;

  int Keff = K;
  if (MODE == 2 && causal) Keff = min(K, rowbase + 128);

  __shared__ u16 As[8192];   // [128][64] u16, chunk-swizzled
  __shared__ u16 Bs[8192];

  const int lane = t & 63;
  const int wv = t >> 6;
  const int wr = wv >> 1;
  const int wc = wv & 1;
  const int quad = lane >> 4;
  const int lr = lane & 15;

  f32x4 acc[4][4];
  const f32x4 zero = {0.f, 0.f, 0.f, 0.f};
#pragma unroll
  for (int i = 0; i < 4; ++i)
#pragma unroll
    for (int j = 0; j < 4; ++j) acc[i][j] = zero;

  {
    const int csw = (t & 7) ^ ((t >> 3) & 7);
    const u16* ga = Ab + (long long)(rowbase + (t >> 3)) * lda + csw * 8;
    const u16* gb = Bb + (long long)(colbase + (t >> 3)) * ldb + csw * 8;
    const long long ra = 32LL * lda, rb = 32LL * ldb;
    u16* la = As + t * 8;
    u16* lb = Bs + t * 8;

    const int m7 = lr & 7;
    const int a_base = (wr * 64 + lr) * 64 + ((quad ^ m7) * 8);
    const int b_base = (wc * 64 + lr) * 64 + ((quad ^ m7) * 8);

    for (int k0 = 0; k0 < Keff; k0 += 64) {
      __syncthreads();               // prior frag reads done before overwrite
#pragma unroll
      for (int i = 0; i < 4; ++i) {
        llds16(ga + k0 + i * ra, la + i * 2048);
        llds16(gb + k0 + i * rb, lb + i * 2048);
      }
      __syncthreads();               // compiler drains vmcnt before barrier
#pragma unroll
      for (int ks = 0; ks < 2; ++ks) {
        const int ko = ks ? 32 : 0;  // slot ^= 4  ->  u16 offset ^ 32
        bf16x8 af[4], bfv[4];
#pragma unroll
        for (int tm = 0; tm < 4; ++tm)
          af[tm] = *(const bf16x8*)(As + ((a_base + tm * 1024) ^ ko));
#pragma unroll
        for (int tn = 0; tn < 4; ++tn)
          bfv[tn] = *(const bf16x8*)(Bs + ((b_base + tn * 1024) ^ ko));
#pragma unroll
        for (int tm = 0; tm < 4; ++tm)
#pragma unroll
          for (int tn = 0; tn < 4; ++tn)
            acc[tm][tn] = __builtin_amdgcn_mfma_f32_16x16x32_bf16(
                af[tm], bfv[tn], acc[tm][tn], 0, 0, 0);
      }
    }
  }

  // ------------------------------ epilogue ------------------------------
  if (MODE == 0 && colbase >= 2048) {
#pragma unroll
    for (int tm = 0; tm < 4; ++tm) {
      int s0 = rowbase + wr * 64 + tm * 16 + quad * 4;
      int b = s0 >> 11;
      int sl = s0 & 2047;
#pragma unroll
      for (int tn = 0; tn < 4; ++tn) {
        int e = colbase - 2048 + wc * 64 + tn * 16 + lr;
        ushort4 o;
        o.x = f2bf(acc[tm][tn][0]);
        o.y = f2bf(acc[tm][tn][1]);
        o.z = f2bf(acc[tm][tn][2]);
        o.w = f2bf(acc[tm][tn][3]);
        *(ushort4*)(vt + ((long long)(b * 1024 + e)) * 2048 + sl) = o;
      }
    }
    return;
  }

#pragma unroll
  for (int tm = 0; tm < 4; ++tm) {
#pragma unroll
    for (int r = 0; r < 4; ++r) {
      const int grow = rowbase + wr * 64 + tm * 16 + quad * 4 + r;
      float li, rsum = 0.f;
      if (MODE == 2) li = __builtin_amdgcn_rcpf(lsum[blockIdx.z * 2048 + grow]);
#pragma unroll
      for (int tn = 0; tn < 4; ++tn) {
        const int gcol = colbase + wc * 64 + tn * 16 + lr;
        float val = acc[tm][tn][r];
        if (MODE == 0) {
          ((u16*)Cp)[(long long)grow * ldc + gcol] = f2bf(val);
        } else if (MODE == 1) {
          u16* C = (u16*)Cp + (long long)blockIdx.z * sC;
          float ex = (causal && gcol > grow) ? 0.f : __expf(val * scale);
          C[(long long)grow * ldc + gcol] = f2bf(ex);
          rsum += ex;
        } else {
          float* C = (float*)Cp + (long long)blockIdx.z * sC;
          C[(long long)grow * ldc + gcol] = val * li;
        }
      }
      if (MODE == 1) {
#pragma unroll
        for (int o = 8; o > 0; o >>= 1) rsum += __shfl_xor(rsum, o, 64);
        if (lr == 0)
          atomicAdd(&lsum[blockIdx.z * 2048 + grow], rsum);
      }
    }
  }
}

// ---------------------------------------------------------------------------
// sc/pv, round-11: SINGLE-WAVE workgroups on 64x64 tiles.
// Mechanism: sc measured 60.5us at MfmaUtil 10.6% — a CU holds ~2
// barrier-locked 4-wave gangs whose vmcnt(0) drains stall all MFMA pipes
// together, 16x per job.  QKV's same loop runs 33% MfmaUtil because more
// independent gangs overlap (m114).  One wave per block = PRIVATE barrier:
// ~8-10 independent waves/CU, each in a different K-phase; no lockstep.
// Wave tile stays 64x64 (r9: smaller wave tiles lose) -> MFMA:ds_read per
// ks unchanged (16:8).  Staging swizzle identical: 8 rows/call, i*8 === 0
// (mod 8) keeps row&7 == (t>>3)&7.  LDS 16KB/block -> 10 blocks/CU cap.
// Logical refetch doubles but qk (64MB) / sb panels are L2/L3-served.
// MODE 1: scores -> exp(s*scale) fused, causal -> 0, row-sums atomicAdd
// MODE 2: PV -> fp32, * rcp(lsum[row]), causal K-truncation
// ---------------------------------------------------------------------------
template<int MODE>
__global__ __launch_bounds__(64) void tile64(
    const u16* __restrict__ A, long long sA, int lda,
    const u16* __restrict__ B, long long sB, int ldb,
    void* __restrict__ Cp, long long sC, int ldc,
    int K, float scale, float* __restrict__ lsum,
    const int* __restrict__ causalp) {
  const int t = threadIdx.x;
  const int causal = causalp[0];

  int rt, ct, zb;
  if (MODE == 1) {
    // S-tile grid: 32x32 per batch, row-major; causal skips upper tiles.
    const int j = blockIdx.x;
    zb = j >> 10;
    const int rem = j & 1023;
    rt = rem >> 5;
    ct = rem & 31;
    if (causal && ct > rt) return;
  } else {
    // out-tile grid: 32 row-tiles x 16 col-tiles x 4 batches, longest-K 1st
    const int j = blockIdx.x;
    zb = j >> 9;
    const int rem = j & 511;
    rt = 31 - (rem >> 4);
    ct = rem & 15;
  }

  const int rowbase = rt * 64;
  const int colbase = ct * 64;
  const u16* Ab = A + (long long)zb * sA;
  const u16* Bb = B + (long long)zb * sB;

  int Keff = K;
  if (MODE == 2 && causal) Keff = min(K, rowbase + 64);

  __shared__ u16 As[4096];   // [64][64] u16, chunk-swizzled
  __shared__ u16 Bs[4096];

  const int quad = t >> 4;
  const int lr = t & 15;

  f32x4 acc[4][4];
  const f32x4 zero = {0.f, 0.f, 0.f, 0.f};
#pragma unroll
  for (int i = 0; i < 4; ++i)
#pragma unroll
    for (int j2 = 0; j2 < 4; ++j2) acc[i][j2] = zero;

  {
    // staging: call i covers rows i*8 + (t>>3); lane fetches global chunk
    // csw = (t&7)^((t>>3)&7) (row&7 == (t>>3)&7 since i*8 % 8 == 0) so the
    // lane-linear DMA write yields slot = chunk^(row&7).
    const int csw = (t & 7) ^ ((t >> 3) & 7);
    const u16* ga = Ab + (long long)(rowbase + (t >> 3)) * lda + csw * 8;
    const u16* gb = Bb + (long long)(colbase + (t >> 3)) * ldb + csw * 8;
    const long long ra = 8LL * lda, rb = 8LL * ldb;
    u16* la = As + t * 8;
    u16* lb = Bs + t * 8;

    // frag read: row = tm*16 + lr (A) / tn*16 + lr (B), chunk = quad+ks*4,
    // slot = chunk ^ (lr&7); ks=1 toggles u16-offset 32
    const int m7 = lr & 7;
    const int fbase = lr * 64 + ((quad ^ m7) * 8);

    for (int k0 = 0; k0 < Keff; k0 += 64) {
      __syncthreads();               // own frag reads done before overwrite
#pragma unroll
      for (int i = 0; i < 8; ++i) {
        llds16(ga + k0 + i * ra, la + i * 512);
        llds16(gb + k0 + i * rb, lb + i * 512);
      }
      __syncthreads();               // compiler drains vmcnt before barrier
#pragma unroll
      for (int ks = 0; ks < 2; ++ks) {
        const int ko = ks ? 32 : 0;  // slot ^= 4  ->  u16 offset ^ 32
        bf16x8 af[4], bfv[4];
#pragma unroll
        for (int tm = 0; tm < 4; ++tm)
          af[tm] = *(const bf16x8*)(As + ((fbase + tm * 1024) ^ ko));
#pragma unroll
        for (int tn = 0; tn < 4; ++tn)
          bfv[tn] = *(const bf16x8*)(Bs + ((fbase + tn * 1024) ^ ko));
#pragma unroll
        for (int tm = 0; tm < 4; ++tm)
#pragma unroll
          for (int tn = 0; tn < 4; ++tn)
            acc[tm][tn] = __builtin_amdgcn_mfma_f32_16x16x32_bf16(
                af[tm], bfv[tn], acc[tm][tn], 0, 0, 0);
      }
    }
  }

  // ------------------------------ epilogue ------------------------------
  // C/D layout (m89/m91): col = lane&15, row = (lane>>4)*4 + reg
#pragma unroll
  for (int tm = 0; tm < 4; ++tm) {
#pragma unroll
    for (int r = 0; r < 4; ++r) {
      const int grow = rowbase + tm * 16 + quad * 4 + r;
      float li, rsum = 0.f;
      if (MODE == 2) li = __builtin_amdgcn_rcpf(lsum[zb * 2048 + grow]);
#pragma unroll
      for (int tn = 0; tn < 4; ++tn) {
        const int gcol = colbase + tn * 16 + lr;
        float val = acc[tm][tn][r];
        if (MODE == 1) {
          u16* C = (u16*)Cp + (long long)zb * sC;
          float ex = (causal && gcol > grow) ? 0.f : __expf(val * scale);
          C[(long long)grow * ldc + gcol] = f2bf(ex);
          rsum += ex;
        } else {
          float* C = (float*)Cp + (long long)zb * sC;
          C[(long long)grow * ldc + gcol] = val * li;
        }
      }
      if (MODE == 1) {
        // reduce across the 16 col-lanes of this row (within the quad),
        // one atomic per row-instance
#pragma unroll
        for (int o = 8; o > 0; o >>= 1) rsum += __shfl_xor(rsum, o, 64);
        if (lr == 0)
          atomicAdd(&lsum[zb * 2048 + grow], rsum);
      }
    }
  }
}

// ---------------------------------------------------------------------------
extern "C" void kernel_launch(void* const* d_in, const int* in_sizes, int n_in,
                              void* d_out, int out_size, void* d_ws, size_t ws_size,
                              hipStream_t stream) {
  const float* x  = (const float*)d_in[0];
  const float* wq = (const float*)d_in[1];
  const float* wk = (const float*)d_in[2];
  const float* wv = (const float*)d_in[3];
  const int* causal = (const int*)d_in[4];
  float* out = (float*)d_out;

  // workspace layout (bytes):
  //   xb 0..16,777,216   wb ..23,068,672   qk ..56,623,104
  //   vt ..73,400,320    sb ..106,954,752  lsum ..106,987,520
  char* ws = (char*)d_ws;
  u16* xb = (u16*)(ws);               // [8192][1024] bf16 x
  u16* wb = (u16*)(ws + 16777216);    // [3072][1024] bf16 Wq|Wk|Wv
  u16* qk = (u16*)(ws + 23068672);    // [8192][2048] bf16 Q|K
  u16* vt = (u16*)(ws + 56623104);    // [4][1024][2048] bf16 V^T
  u16* sb = (u16*)(ws + 73400320);    // [4][2048][2048] bf16 exp-scores
  float* lsum = (float*)(ws + 106954752);  // [4][2048] softmax denominators

  // casts (x, wq, wk, wv -> bf16) + lsum zero-init, one launch
  cast_all<<<11264, 256, 0, stream>>>(x, wq, wk, wv, xb, wb, lsum);

  // QKV: [8192 x 3072] = xb @ wb^T ; Q,K -> qk, V -> vt (transposed)
  gemm_nt<0><<<dim3(64, 24, 1), 256, 0, stream>>>(
      xb, 0, 1024, wb, 0, 1024, qk, 0, 2048, 1024, vt, 1.0f, nullptr, causal);

  // exp-scores: 64x64 tiles, one wave per block (4096 blocks; causal keeps
  // the 2112 lower-tri ones, upper return instantly)
  tile64<1><<<dim3(4096, 1, 1), 64, 0, stream>>>(
      qk, 2048LL * 2048, 2048, qk + 1024, 2048LL * 2048, 2048,
      sb, 2048LL * 2048, 2048, 1024, 0.03125f, lsum, causal);

  // out: 64x64 tiles, one wave per block (2048 blocks, longest-K first)
  tile64<2><<<dim3(2048, 1, 1), 64, 0, stream>>>(
      sb, 2048LL * 2048, 2048, vt, 1024LL * 2048, 2048,
      out, 2048LL * 1024, 1024, 2048, 1.0f, lsum, causal);
}